// Round 1
// baseline (8038.931 us; speedup 1.0000x reference)
//
#include <hip/hip_runtime.h>

#define T_TOTAL 131072
#define NH1 64
#define NH2 32
#define NS 64

// ---------------------------------------------------------------------------
// Kernel 1: MLP priors.  llr[t][s] = -( relu(relu(x*W1+b1)@W2+b2)@W3+b3 )[s]
// ---------------------------------------------------------------------------
__global__ __launch_bounds__(256) void mlp_kernel(
    const float* __restrict__ rx, const float* __restrict__ W1,
    const float* __restrict__ b1, const float* __restrict__ W2,
    const float* __restrict__ b2, const float* __restrict__ W3,
    const float* __restrict__ b3, float* __restrict__ llr, int n) {
#pragma clang fp contract(on)   // fuse only within expressions (keep bias adds separate)
  __shared__ float sW2[NH1 * NH2], sW3[NH2 * NS];
  __shared__ float sW1[NH1], sb1[NH1], sb2[NH2], sb3[NS];
  int tid = threadIdx.x;
  for (int i = tid; i < NH1 * NH2; i += 256) sW2[i] = W2[i];
  for (int i = tid; i < NH2 * NS; i += 256) sW3[i] = W3[i];
  if (tid < NH1) { sW1[tid] = W1[tid]; sb1[tid] = b1[tid]; }
  if (tid < NH2) sb2[tid] = b2[tid];
  if (tid < NS)  sb3[tid] = b3[tid];
  __syncthreads();

  int t = blockIdx.x * 256 + tid;
  if (t >= n) return;
  float x = rx[t];

  float h1[NH1];
#pragma unroll
  for (int j = 0; j < NH1; ++j) {
    float p = x * sW1[j];
    float s = p + sb1[j];
    h1[j] = fmaxf(s, 0.0f);
  }
  float h2[NH2];
#pragma unroll
  for (int k = 0; k < NH2; ++k) {
    float acc = 0.0f;
#pragma unroll
    for (int j = 0; j < NH1; ++j) acc += h1[j] * sW2[j * NH2 + k];
    float s = acc + sb2[k];
    h2[k] = fmaxf(s, 0.0f);
  }
#pragma unroll
  for (int s_ = 0; s_ < NS; ++s_) {
    float acc = 0.0f;
#pragma unroll
    for (int k = 0; k < NH2; ++k) acc += h2[k] * sW3[k * NS + s_];
    float o = acc + sb3[s_];
    llr[(size_t)t * NS + s_] = -o;
  }
}

// ---------------------------------------------------------------------------
// Kernel 2: the sequential Viterbi metric recurrence.  One wave, lane i = state i.
// Stores the PRE-update metric row (states 0..31 only; state i == state i+32
// by construction of the transition table) so the argmin is done in parallel
// by kernel 3 instead of on this wave's critical chain.
// Exact fp32 op order:  v = prob + llr_t ;  prob' = min(v[2i&63], v[(2i+1)&63])
// ---------------------------------------------------------------------------
__global__ __launch_bounds__(64) void scan_kernel(
    const float* __restrict__ llr, float* __restrict__ traj,
    float* __restrict__ state, int nsteps, int first) {
  const int lane = threadIdx.x;
  const int a0 = ((2 * lane) & 63) * 4;        // byte addr for ds_bpermute
  const int a1 = ((2 * lane + 1) & 63) * 4;
  float prob = first ? 0.0f : state[lane];
  const float* lp = llr + lane;
  float* tp = traj + (lane & 31);
  const bool lo = (lane < 32);

  float q[8];
#pragma unroll
  for (int i = 0; i < 8; ++i) q[i] = lp[i * 64];
  lp += 8 * 64;

  for (int t = 0; t < nsteps; t += 8) {
    float nq[8];
#pragma unroll
    for (int i = 0; i < 8; ++i) nq[i] = lp[i * 64];   // prefetch next group (padded buf)
    lp += 8 * 64;
#pragma unroll
    for (int i = 0; i < 8; ++i) {
      if (lo) tp[0] = prob;                            // pre-update row -> traj
      tp += 32;
      float v = prob + q[i];
      int g0 = __builtin_amdgcn_ds_bpermute(a0, __float_as_int(v));
      int g1 = __builtin_amdgcn_ds_bpermute(a1, __float_as_int(v));
      prob = fminf(__int_as_float(g0), __int_as_float(g1));
    }
#pragma unroll
    for (int i = 0; i < 8; ++i) q[i] = nq[i];
  }
  state[lane] = prob;
}

// ---------------------------------------------------------------------------
// Kernel 3: bits[t] = parity of argmin (first-index tie-break) of traj row t.
// ---------------------------------------------------------------------------
__global__ __launch_bounds__(256) void bits_kernel(
    const float* __restrict__ traj, float* __restrict__ out, int n) {
  int t = blockIdx.x * 256 + threadIdx.x;
  if (t >= n) return;
  float v[32];
  const float4* row = (const float4*)(traj + (size_t)t * 32);
#pragma unroll
  for (int j = 0; j < 8; ++j) ((float4*)v)[j] = row[j];
  float best = v[0];
  int bi = 0;
#pragma unroll
  for (int i = 1; i < 32; ++i) {
    if (v[i] < best) { best = v[i]; bi = i; }          // strict <  => lowest index wins
  }
  out[t] = (float)(bi & 1);
}

// ---------------------------------------------------------------------------
extern "C" void kernel_launch(void* const* d_in, const int* in_sizes, int n_in,
                              void* d_out, int out_size, void* d_ws, size_t ws_size,
                              hipStream_t stream) {
  const float* rx = (const float*)d_in[0];
  const float* W1 = (const float*)d_in[1];
  const float* b1 = (const float*)d_in[2];
  const float* W2 = (const float*)d_in[3];
  const float* b2 = (const float*)d_in[4];
  const float* W3 = (const float*)d_in[5];
  const float* b3 = (const float*)d_in[6];
  float* out = (float*)d_out;

  // Pick the largest chunk whose llr(+8 pad rows) + traj + state fit in ws.
  int CH = 1024;
  for (int c = T_TOTAL; c >= 1024; c >>= 1) {
    size_t need = ((size_t)(c + 8) * 64 + (size_t)c * 32 + 64) * sizeof(float);
    if (need <= ws_size) { CH = c; break; }
  }

  float* llr   = (float*)d_ws;                       // (CH+8) x 64
  float* traj  = llr + (size_t)(CH + 8) * 64;        // CH x 32
  float* state = traj + (size_t)CH * 32;             // 64

  for (int t0 = 0; t0 < T_TOTAL; t0 += CH) {
    mlp_kernel<<<CH / 256, 256, 0, stream>>>(rx + t0, W1, b1, W2, b2, W3, b3, llr, CH);
    scan_kernel<<<1, 64, 0, stream>>>(llr, traj, state, CH, (t0 == 0) ? 1 : 0);
    bits_kernel<<<CH / 256, 256, 0, stream>>>(traj, out + t0, CH);
  }
}

// Round 2
// 5287.740 us; speedup vs baseline: 1.5203x; 1.5203x over previous
//
#include <hip/hip_runtime.h>

#define T_TOTAL 131072
#define NH1 64
#define NH2 32
#define NS 64
#define PF_D 8   // scan prefetch depth, in 4-step groups

// ---------------------------------------------------------------------------
// Kernel 1: MLP priors.  llr[t][s] = -( relu(relu(x*W1+b1)@W2+b2)@W3+b3 )[s]
// UNCHANGED from round 1 (passed with absmax 0.0) — do not perturb arithmetic.
// ---------------------------------------------------------------------------
__global__ __launch_bounds__(256) void mlp_kernel(
    const float* __restrict__ rx, const float* __restrict__ W1,
    const float* __restrict__ b1, const float* __restrict__ W2,
    const float* __restrict__ b2, const float* __restrict__ W3,
    const float* __restrict__ b3, float* __restrict__ llr, int n) {
#pragma clang fp contract(on)
  __shared__ float sW2[NH1 * NH2], sW3[NH2 * NS];
  __shared__ float sW1[NH1], sb1[NH1], sb2[NH2], sb3[NS];
  int tid = threadIdx.x;
  for (int i = tid; i < NH1 * NH2; i += 256) sW2[i] = W2[i];
  for (int i = tid; i < NH2 * NS; i += 256) sW3[i] = W3[i];
  if (tid < NH1) { sW1[tid] = W1[tid]; sb1[tid] = b1[tid]; }
  if (tid < NH2) sb2[tid] = b2[tid];
  if (tid < NS)  sb3[tid] = b3[tid];
  __syncthreads();

  int t = blockIdx.x * 256 + tid;
  if (t >= n) return;
  float x = rx[t];

  float h1[NH1];
#pragma unroll
  for (int j = 0; j < NH1; ++j) {
    float p = x * sW1[j];
    float s = p + sb1[j];
    h1[j] = fmaxf(s, 0.0f);
  }
  float h2[NH2];
#pragma unroll
  for (int k = 0; k < NH2; ++k) {
    float acc = 0.0f;
#pragma unroll
    for (int j = 0; j < NH1; ++j) acc += h1[j] * sW2[j * NH2 + k];
    float s = acc + sb2[k];
    h2[k] = fmaxf(s, 0.0f);
  }
#pragma unroll
  for (int s_ = 0; s_ < NS; ++s_) {
    float acc = 0.0f;
#pragma unroll
    for (int k = 0; k < NH2; ++k) acc += h2[k] * sW3[k * NS + s_];
    float o = acc + sb3[s_];
    llr[(size_t)t * NS + s_] = -o;
  }
}

// ---------------------------------------------------------------------------
// Kernel 2: pack llr rows 4g+1..4g+3 into the per-lane gather layout consumed
// by the scan's k=4 sub-trellis tree.  packed[(g*4+q)*64 + lane] (float4):
//   q0 = R2[(8l+0..3)&63], q1 = R2[(8l+4..7)&63],
//   q2 = R3[(4l+0..3)&63], q3 = (R4[(2l)&63], R4[(2l+1)&63], 0, 0)
// ---------------------------------------------------------------------------
__global__ __launch_bounds__(256) void pack_kernel(
    const float* __restrict__ llrnat, float4* __restrict__ packed, int ngroups) {
  int id = blockIdx.x * 256 + threadIdx.x;
  if (id >= ngroups * 64) return;
  int g = id >> 6, lane = id & 63;
  const float* R2 = llrnat + (size_t)(4 * g + 1) * 64;
  const float* R3 = llrnat + (size_t)(4 * g + 2) * 64;
  const float* R4 = llrnat + (size_t)(4 * g + 3) * 64;
  int b8 = (8 * lane) & 63;   // +7 never wraps past 63
  int b4 = (4 * lane) & 63;
  int b2 = (2 * lane) & 63;
  float4 q0, q1, q2, q3;
  q0.x = R2[b8];     q0.y = R2[b8 + 1]; q0.z = R2[b8 + 2]; q0.w = R2[b8 + 3];
  q1.x = R2[b8 + 4]; q1.y = R2[b8 + 5]; q1.z = R2[b8 + 6]; q1.w = R2[b8 + 7];
  q2.x = R3[b4];     q2.y = R3[b4 + 1]; q2.z = R3[b4 + 2]; q2.w = R3[b4 + 3];
  q3.x = R4[b2];     q3.y = R4[b2 + 1]; q3.z = 0.0f;       q3.w = 0.0f;
  size_t base = ((size_t)g * 4) * 64 + lane;
  packed[base]       = q0;
  packed[base + 64]  = q1;
  packed[base + 128] = q2;
  packed[base + 192] = q3;
}

// ---------------------------------------------------------------------------
// Kernel 3: sequential Viterbi recurrence, 4 steps per cross-lane roundtrip.
// Exact fp32 replay of the reference (min-plus distributivity is exact):
//   A[s]   = prob[s] + R1[s]                      (the reference step-1 add)
//   W[s]   = min(A[s], A[s^1])    via DPP         (reference step-1 min; the
//            value at even lane 2j is node N1[j])
//   gather N1[(8i+u)&63] from lane (16i+2u)&63    (8 parallel bpermutes)
//   3 local tree levels, each doing the reference's add(pred llr) + min.
// Stores only group-boundary metric rows; bits_kernel rebuilds the rest.
// ---------------------------------------------------------------------------
__global__ __launch_bounds__(64) void scan_kernel(
    const float* __restrict__ llrnat, const float4* __restrict__ packed,
    float* __restrict__ trajb, float* __restrict__ state, int ngroups, int first) {
  const int lane = threadIdx.x;
  int a[8];
#pragma unroll
  for (int u = 0; u < 8; ++u) a[u] = (((lane << 4) + 2 * u) & 63) << 2;
  float prob = first ? 0.0f : state[lane];

  // software pipeline: PF_D groups in flight, compile-time slot indices
  float  R[PF_D];
  float4 Q0[PF_D], Q1[PF_D], Q2[PF_D], Q3[PF_D];
#pragma unroll
  for (int j = 0; j < PF_D; ++j) {
    R[j] = llrnat[(size_t)(4 * j) * 64 + lane];
    size_t b = ((size_t)j * 4) * 64 + lane;
    Q0[j] = packed[b]; Q1[j] = packed[b + 64];
    Q2[j] = packed[b + 128]; Q3[j] = packed[b + 192];
  }

  for (int G = 0; G < ngroups; G += PF_D) {
#pragma unroll
    for (int j = 0; j < PF_D; ++j) {
      const int g = G + j;
      const float  r1 = R[j];
      const float4 q0 = Q0[j], q1 = Q1[j], q2 = Q2[j], q3 = Q3[j];
      // refill slot with group g+PF_D (pads allocated past the end)
      {
        const int gp = g + PF_D;
        R[j] = llrnat[(size_t)(4 * gp) * 64 + lane];
        size_t b = ((size_t)gp * 4) * 64 + lane;
        Q0[j] = packed[b]; Q1[j] = packed[b + 64];
        Q2[j] = packed[b + 128]; Q3[j] = packed[b + 192];
      }

      if (lane < 32) trajb[(size_t)g * 32 + lane] = prob;  // row t=4g (pre-update)

      float A = prob + r1;
      int Bi = __builtin_amdgcn_mov_dpp(__float_as_int(A), 0xB1, 0xF, 0xF, true); // quad_perm [1,0,3,2]
      float W = fminf(A, __int_as_float(Bi));
      int wi = __float_as_int(W);
      float n1_0 = __int_as_float(__builtin_amdgcn_ds_bpermute(a[0], wi));
      float n1_1 = __int_as_float(__builtin_amdgcn_ds_bpermute(a[1], wi));
      float n1_2 = __int_as_float(__builtin_amdgcn_ds_bpermute(a[2], wi));
      float n1_3 = __int_as_float(__builtin_amdgcn_ds_bpermute(a[3], wi));
      float n1_4 = __int_as_float(__builtin_amdgcn_ds_bpermute(a[4], wi));
      float n1_5 = __int_as_float(__builtin_amdgcn_ds_bpermute(a[5], wi));
      float n1_6 = __int_as_float(__builtin_amdgcn_ds_bpermute(a[6], wi));
      float n1_7 = __int_as_float(__builtin_amdgcn_ds_bpermute(a[7], wi));
      // level 2: states (4i+v)&63 at t+2
      float n2_0 = fminf(n1_0 + q0.x, n1_1 + q0.y);
      float n2_1 = fminf(n1_2 + q0.z, n1_3 + q0.w);
      float n2_2 = fminf(n1_4 + q1.x, n1_5 + q1.y);
      float n2_3 = fminf(n1_6 + q1.z, n1_7 + q1.w);
      // level 3: states (2i+w)&63 at t+3
      float n3_0 = fminf(n2_0 + q2.x, n2_1 + q2.y);
      float n3_1 = fminf(n2_2 + q2.z, n2_3 + q2.w);
      // level 4: state i at t+4
      prob = fminf(n3_0 + q3.x, n3_1 + q3.y);
    }
  }
  state[lane] = prob;
}

// ---------------------------------------------------------------------------
// Kernel 4: per-t bit.  Rebuild row t from boundary row 4g with r=t&3 local
// trellis steps (exact reference op order), then strict-< argmin parity.
// ---------------------------------------------------------------------------
__global__ __launch_bounds__(256) void bits_kernel(
    const float* __restrict__ trajb, const float* __restrict__ llrnat,
    float* __restrict__ out, int n) {
  int t = blockIdx.x * 256 + threadIdx.x;
  if (t >= n) return;
  int g = t >> 2, r = t & 3;
  float cur[32];
  const float4* row = (const float4*)(trajb + (size_t)g * 32);
#pragma unroll
  for (int j = 0; j < 8; ++j) ((float4*)cur)[j] = row[j];
  for (int p = 0; p < r; ++p) {
    const float* L = llrnat + (size_t)(4 * g + p) * 64;
    float nw[32];
#pragma unroll
    for (int j = 0; j < 32; ++j) {
      nw[j] = fminf(cur[(2 * j) & 31] + L[2 * j], cur[(2 * j + 1) & 31] + L[2 * j + 1]);
    }
#pragma unroll
    for (int j = 0; j < 32; ++j) cur[j] = nw[j];
  }
  float best = cur[0]; int bi = 0;
#pragma unroll
  for (int i = 1; i < 32; ++i) {
    if (cur[i] < best) { best = cur[i]; bi = i; }   // first-index tie-break
  }
  out[t] = (float)(bi & 1);
}

// ---------------------------------------------------------------------------
extern "C" void kernel_launch(void* const* d_in, const int* in_sizes, int n_in,
                              void* d_out, int out_size, void* d_ws, size_t ws_size,
                              hipStream_t stream) {
  const float* rx = (const float*)d_in[0];
  const float* W1 = (const float*)d_in[1];
  const float* b1 = (const float*)d_in[2];
  const float* W2 = (const float*)d_in[3];
  const float* b2 = (const float*)d_in[4];
  const float* W3 = (const float*)d_in[5];
  const float* b3 = (const float*)d_in[6];
  float* out = (float*)d_out;

  // chunk: llrnat (CH+4*PF_D rows x 64) + packed ((CH/4+PF_D)*4*64 float4)
  //        + trajb (CH/4 x 32) + state(64)
  int CH = 4096;
  for (int c = T_TOTAL; c >= 4096; c >>= 1) {
    size_t llrn = ((size_t)c + 4 * PF_D) * 64 * sizeof(float);
    size_t pk   = ((size_t)c / 4 + PF_D) * 4 * 64 * sizeof(float4);
    size_t tb   = ((size_t)c / 4) * 32 * sizeof(float);
    if (llrn + pk + tb + 4096 <= ws_size) { CH = c; break; }
  }
  const int ngroups = CH / 4;

  float*  llrnat = (float*)d_ws;
  float4* packed = (float4*)((char*)d_ws + ((size_t)CH + 4 * PF_D) * 64 * sizeof(float));
  float*  trajb  = (float*)((char*)packed + ((size_t)ngroups + PF_D) * 4 * 64 * sizeof(float4));
  float*  state  = trajb + (size_t)ngroups * 32;

  for (int t0 = 0; t0 < T_TOTAL; t0 += CH) {
    mlp_kernel <<<CH / 256, 256, 0, stream>>>(rx + t0, W1, b1, W2, b2, W3, b3, llrnat, CH);
    pack_kernel<<<CH / 16, 256, 0, stream>>>(llrnat, packed, ngroups);
    scan_kernel<<<1, 64, 0, stream>>>(llrnat, packed, trajb, state, ngroups, (t0 == 0) ? 1 : 0);
    bits_kernel<<<CH / 256, 256, 0, stream>>>(trajb, llrnat, out + t0, CH);
  }
}

// Round 3
// 4361.181 us; speedup vs baseline: 1.8433x; 1.2125x over previous
//
#include <hip/hip_runtime.h>

#define T_TOTAL 131072
#define NH1 64
#define NH2 32
#define NS 64
#define PF_D 8   // scan prefetch depth, in 4-step groups

// ---------------------------------------------------------------------------
// Kernel 1: MLP priors.  llr[t][s] = -( relu(relu(x*W1+b1)@W2+b2)@W3+b3 )[s]
// UNCHANGED since round 1 (absmax 0.0) — do not perturb arithmetic.
// ---------------------------------------------------------------------------
__global__ __launch_bounds__(256) void mlp_kernel(
    const float* __restrict__ rx, const float* __restrict__ W1,
    const float* __restrict__ b1, const float* __restrict__ W2,
    const float* __restrict__ b2, const float* __restrict__ W3,
    const float* __restrict__ b3, float* __restrict__ llr, int n) {
#pragma clang fp contract(on)
  __shared__ float sW2[NH1 * NH2], sW3[NH2 * NS];
  __shared__ float sW1[NH1], sb1[NH1], sb2[NH2], sb3[NS];
  int tid = threadIdx.x;
  for (int i = tid; i < NH1 * NH2; i += 256) sW2[i] = W2[i];
  for (int i = tid; i < NH2 * NS; i += 256) sW3[i] = W3[i];
  if (tid < NH1) { sW1[tid] = W1[tid]; sb1[tid] = b1[tid]; }
  if (tid < NH2) sb2[tid] = b2[tid];
  if (tid < NS)  sb3[tid] = b3[tid];
  __syncthreads();

  int t = blockIdx.x * 256 + tid;
  if (t >= n) return;
  float x = rx[t];

  float h1[NH1];
#pragma unroll
  for (int j = 0; j < NH1; ++j) {
    float p = x * sW1[j];
    float s = p + sb1[j];
    h1[j] = fmaxf(s, 0.0f);
  }
  float h2[NH2];
#pragma unroll
  for (int k = 0; k < NH2; ++k) {
    float acc = 0.0f;
#pragma unroll
    for (int j = 0; j < NH1; ++j) acc += h1[j] * sW2[j * NH2 + k];
    float s = acc + sb2[k];
    h2[k] = fmaxf(s, 0.0f);
  }
#pragma unroll
  for (int s_ = 0; s_ < NS; ++s_) {
    float acc = 0.0f;
#pragma unroll
    for (int k = 0; k < NH2; ++k) acc += h2[k] * sW3[k * NS + s_];
    float o = acc + sb3[s_];
    llr[(size_t)t * NS + s_] = -o;
  }
}

// ---------------------------------------------------------------------------
// Kernel 2: sequential Viterbi recurrence, 4 steps per cross-lane roundtrip.
// Exact fp32 replay of the reference (min-plus distributivity is exact).
// llr tree operands are loaded straight from llrnat with broadcast addressing:
//   q0/q1 = R2[8*(l&7)+0..7], q2 = R3[4*(l&15)+0..3], q3 = R4[2*(l&31)+0..1]
// (identical values to round-2's packed buffer — same ops, same order).
// Boundary metric rows go to a TRANSPOSED traj buffer, batched 4 groups per
// float4 store to keep vmcnt/WAR pressure off the dependent chain.
// ---------------------------------------------------------------------------
__global__ __launch_bounds__(64) void scan_kernel(
    const float* __restrict__ llrnat, float* __restrict__ trajt,
    float* __restrict__ state, int ngroups, int first) {
  const int lane = threadIdx.x;
  int a[8];
#pragma unroll
  for (int u = 0; u < 8; ++u) a[u] = (((lane << 4) + 2 * u) & 63) << 2;
  const int o0 = 64 + 8 * (lane & 7);     // into R2
  const int o2 = 128 + 4 * (lane & 15);   // into R3
  const int o3 = 192 + 2 * (lane & 31);   // into R4
  float prob = first ? 0.0f : state[lane];

  // software pipeline: PF_D groups in flight, compile-time slot indices
  float  R[PF_D];
  float4 Q0[PF_D], Q1[PF_D], Q2[PF_D];
  float2 Q3[PF_D];
#pragma unroll
  for (int j = 0; j < PF_D; ++j) {
    const float* gb = llrnat + (size_t)j * 256;
    R[j]  = gb[lane];
    Q0[j] = *(const float4*)(gb + o0);
    Q1[j] = *(const float4*)(gb + o0 + 4);
    Q2[j] = *(const float4*)(gb + o2);
    Q3[j] = *(const float2*)(gb + o3);
  }

  float p0 = 0.0f, p1 = 0.0f, p2 = 0.0f;
  for (int G = 0; G < ngroups; G += PF_D) {
#pragma unroll
    for (int j = 0; j < PF_D; ++j) {
      const float  r1 = R[j];
      const float4 q0 = Q0[j], q1 = Q1[j], q2 = Q2[j];
      const float2 q3 = Q3[j];
      // refill slot with group G+j+PF_D (pad rows allocated past the end)
      {
        const float* gb = llrnat + (size_t)(G + j + PF_D) * 256;
        R[j]  = gb[lane];
        Q0[j] = *(const float4*)(gb + o0);
        Q1[j] = *(const float4*)(gb + o0 + 4);
        Q2[j] = *(const float4*)(gb + o2);
        Q3[j] = *(const float2*)(gb + o3);
      }

      // boundary row t=4(G+j) (pre-update), batched 4 groups per store
      if ((j & 3) == 0) p0 = prob;
      else if ((j & 3) == 1) p1 = prob;
      else if ((j & 3) == 2) p2 = prob;
      else if (lane < 32) {
        float4 pv = make_float4(p0, p1, p2, prob);
        *(float4*)(trajt + (size_t)lane * ngroups + (G + j - 3)) = pv;
      }

      float A = prob + r1;
      int Bi = __builtin_amdgcn_mov_dpp(__float_as_int(A), 0xB1, 0xF, 0xF, true); // quad_perm [1,0,3,2]
      float W = fminf(A, __int_as_float(Bi));
      int wi = __float_as_int(W);
      float n1_0 = __int_as_float(__builtin_amdgcn_ds_bpermute(a[0], wi));
      float n1_1 = __int_as_float(__builtin_amdgcn_ds_bpermute(a[1], wi));
      float n1_2 = __int_as_float(__builtin_amdgcn_ds_bpermute(a[2], wi));
      float n1_3 = __int_as_float(__builtin_amdgcn_ds_bpermute(a[3], wi));
      float n1_4 = __int_as_float(__builtin_amdgcn_ds_bpermute(a[4], wi));
      float n1_5 = __int_as_float(__builtin_amdgcn_ds_bpermute(a[5], wi));
      float n1_6 = __int_as_float(__builtin_amdgcn_ds_bpermute(a[6], wi));
      float n1_7 = __int_as_float(__builtin_amdgcn_ds_bpermute(a[7], wi));
      // level 2: states (4i+v)&63 at t+2
      float n2_0 = fminf(n1_0 + q0.x, n1_1 + q0.y);
      float n2_1 = fminf(n1_2 + q0.z, n1_3 + q0.w);
      float n2_2 = fminf(n1_4 + q1.x, n1_5 + q1.y);
      float n2_3 = fminf(n1_6 + q1.z, n1_7 + q1.w);
      // level 3: states (2i+w)&63 at t+3
      float n3_0 = fminf(n2_0 + q2.x, n2_1 + q2.y);
      float n3_1 = fminf(n2_2 + q2.z, n2_3 + q2.w);
      // level 4: state i at t+4
      prob = fminf(n3_0 + q3.x, n3_1 + q3.y);
    }
  }
  state[lane] = prob;
}

// ---------------------------------------------------------------------------
// Kernel 3: per-t bit.  Rebuild row t from boundary row 4g with r=t&3 local
// trellis steps (exact reference op order), then strict-< argmin parity.
// trajt is transposed: trajt[state][group].
// ---------------------------------------------------------------------------
__global__ __launch_bounds__(256) void bits_kernel(
    const float* __restrict__ trajt, const float* __restrict__ llrnat,
    float* __restrict__ out, int n, int ngroups) {
  int t = blockIdx.x * 256 + threadIdx.x;
  if (t >= n) return;
  int g = t >> 2, r = t & 3;
  float cur[32];
#pragma unroll
  for (int j = 0; j < 32; ++j) cur[j] = trajt[(size_t)j * ngroups + g];
  for (int p = 0; p < r; ++p) {
    const float* L = llrnat + (size_t)(4 * g + p) * 64;
    float nw[32];
#pragma unroll
    for (int j = 0; j < 32; ++j) {
      nw[j] = fminf(cur[(2 * j) & 31] + L[2 * j], cur[(2 * j + 1) & 31] + L[2 * j + 1]);
    }
#pragma unroll
    for (int j = 0; j < 32; ++j) cur[j] = nw[j];
  }
  float best = cur[0]; int bi = 0;
#pragma unroll
  for (int i = 1; i < 32; ++i) {
    if (cur[i] < best) { best = cur[i]; bi = i; }   // first-index tie-break
  }
  out[t] = (float)(bi & 1);
}

// ---------------------------------------------------------------------------
extern "C" void kernel_launch(void* const* d_in, const int* in_sizes, int n_in,
                              void* d_out, int out_size, void* d_ws, size_t ws_size,
                              hipStream_t stream) {
  const float* rx = (const float*)d_in[0];
  const float* W1 = (const float*)d_in[1];
  const float* b1 = (const float*)d_in[2];
  const float* W2 = (const float*)d_in[3];
  const float* b2 = (const float*)d_in[4];
  const float* W3 = (const float*)d_in[5];
  const float* b3 = (const float*)d_in[6];
  float* out = (float*)d_out;

  // ws: llrnat (CH + 4*PF_D rows x 64) + trajt (32 x CH/4) + state(64)
  int CH = 4096;
  for (int c = T_TOTAL; c >= 4096; c >>= 1) {
    size_t llrn = ((size_t)c + 4 * PF_D) * 64 * sizeof(float);
    size_t tb   = 32 * ((size_t)c / 4) * sizeof(float);
    if (llrn + tb + 4096 <= ws_size) { CH = c; break; }
  }
  const int ngroups = CH / 4;

  float* llrnat = (float*)d_ws;
  float* trajt  = llrnat + ((size_t)CH + 4 * PF_D) * 64;
  float* state  = trajt + (size_t)32 * ngroups;

  for (int t0 = 0; t0 < T_TOTAL; t0 += CH) {
    mlp_kernel <<<CH / 256, 256, 0, stream>>>(rx + t0, W1, b1, W2, b2, W3, b3, llrnat, CH);
    scan_kernel<<<1, 64, 0, stream>>>(llrnat, trajt, state, ngroups, (t0 == 0) ? 1 : 0);
    bits_kernel<<<CH / 256, 256, 0, stream>>>(trajt, llrnat, out + t0, CH, ngroups);
  }
}

// Round 5
// 3203.306 us; speedup vs baseline: 2.5096x; 1.3615x over previous
//
#include <hip/hip_runtime.h>

#define T_TOTAL 131072
#define NH1 64
#define NH2 32
#define NS 64
#define PF_B 4            // prefetch depth in 3-group (12-step) blocks
#define PAD_F ((PF_B + 1) * 768)

// ---------------------------------------------------------------------------
// Kernel 1: MLP priors.  llr[t][s] = -( relu(relu(x*W1+b1)@W2+b2)@W3+b3 )[s]
// UNCHANGED since round 1 (absmax 0.0) — do not perturb arithmetic.
// ---------------------------------------------------------------------------
__global__ __launch_bounds__(256) void mlp_kernel(
    const float* __restrict__ rx, const float* __restrict__ W1,
    const float* __restrict__ b1, const float* __restrict__ W2,
    const float* __restrict__ b2, const float* __restrict__ W3,
    const float* __restrict__ b3, float* __restrict__ llr, int n) {
#pragma clang fp contract(on)
  __shared__ float sW2[NH1 * NH2], sW3[NH2 * NS];
  __shared__ float sW1[NH1], sb1[NH1], sb2[NH2], sb3[NS];
  int tid = threadIdx.x;
  for (int i = tid; i < NH1 * NH2; i += 256) sW2[i] = W2[i];
  for (int i = tid; i < NH2 * NS; i += 256) sW3[i] = W3[i];
  if (tid < NH1) { sW1[tid] = W1[tid]; sb1[tid] = b1[tid]; }
  if (tid < NH2) sb2[tid] = b2[tid];
  if (tid < NS)  sb3[tid] = b3[tid];
  __syncthreads();

  int t = blockIdx.x * 256 + tid;
  if (t >= n) return;
  float x = rx[t];

  float h1[NH1];
#pragma unroll
  for (int j = 0; j < NH1; ++j) {
    float p = x * sW1[j];
    float s = p + sb1[j];
    h1[j] = fmaxf(s, 0.0f);
  }
  float h2[NH2];
#pragma unroll
  for (int k = 0; k < NH2; ++k) {
    float acc = 0.0f;
#pragma unroll
    for (int j = 0; j < NH1; ++j) acc += h1[j] * sW2[j * NH2 + k];
    float s = acc + sb2[k];
    h2[k] = fmaxf(s, 0.0f);
  }
#pragma unroll
  for (int s_ = 0; s_ < NS; ++s_) {
    float acc = 0.0f;
#pragma unroll
    for (int k = 0; k < NH2; ++k) acc += h2[k] * sW3[k * NS + s_];
    float o = acc + sb3[s_];
    llr[(size_t)t * NS + s_] = -o;
  }
}

// ---------------------------------------------------------------------------
// Cross-lane pair-min helpers.  All SYMMETRIC (convention-independent).
// ---------------------------------------------------------------------------
#define DPPF(x, c) __builtin_amdgcn_mov_dpp((x), (c), 0xF, 0xF, true)
__device__ __forceinline__ float xf1(float v) { return __int_as_float(DPPF(__float_as_int(v), 0xB1)); }              // ^1
__device__ __forceinline__ float xf2(float v) { return __int_as_float(DPPF(__float_as_int(v), 0x4E)); }              // ^2
__device__ __forceinline__ float xf4(float v) { return __int_as_float(DPPF(DPPF(__float_as_int(v), 0x141), 0x1B)); } // ^7,^3 = ^4
__device__ __forceinline__ float xf8(float v) { return __int_as_float(DPPF(DPPF(__float_as_int(v), 0x140), 0x141)); }// ^15,^7 = ^8
#define MINX1(v) fminf((v), xf1(v))
#define MINX2(v) fminf((v), xf2(v))
#define MINX4(v) fminf((v), xf4(v))
#define MINX8(v) fminf((v), xf8(v))

typedef unsigned int uint2v __attribute__((ext_vector_type(2)));
#if __has_builtin(__builtin_amdgcn_permlane16_swap) && __has_builtin(__builtin_amdgcn_permlane32_swap)
__device__ __forceinline__ float minx16(float v) {
  uint2v pr = __builtin_amdgcn_permlane16_swap(__float_as_uint(v), __float_as_uint(v), false, false);
  return fminf(__uint_as_float(pr[0]), __uint_as_float(pr[1]));  // = min(x[l], x[l^16]) either convention
}
__device__ __forceinline__ float minx32(float v) {
  uint2v pr = __builtin_amdgcn_permlane32_swap(__float_as_uint(v), __float_as_uint(v), false, false);
  return fminf(__uint_as_float(pr[0]), __uint_as_float(pr[1]));  // = min(x[l], x[l^32])
}
#else
__device__ __forceinline__ float minx16(float v) {
  int a = (((int)threadIdx.x ^ 16) & 63) << 2;
  return fminf(v, __int_as_float(__builtin_amdgcn_ds_bpermute(a, __float_as_int(v))));
}
__device__ __forceinline__ float minx32(float v) {
  int a = (((int)threadIdx.x ^ 32) & 63) << 2;
  return fminf(v, __int_as_float(__builtin_amdgcn_ds_bpermute(a, __float_as_int(v))));
}
#endif

// ---------------------------------------------------------------------------
// Kernel 2: sequential Viterbi recurrence, 4 steps/group, ZERO distribute.
// Rotating lane layout sigma_p (p = group%3), cycle closes every 3 groups:
//   sigma0: s0@l3 s1@l4 s2@l5 s3@l2 s4@l1 s5@l0
//   sigma1: s0@l1 s1@l0 s2@l3 s3@l4 s4@l5 s5@l2
//   sigma2: s0@l5 s1@l2 s2@l1 s3@l0 s4@l3 s5@l4
// Per group (exact fp32 reference op replay; min-plus distributes exactly):
//   A=prob+R1; pair-min over s0-bit; then 3x { +R_k ; pair-min over c_k-bit }
// with freed reduction bits reused as the next state bits.  Reduce masks:
//   p0: ^8 ^16 ^32 ^4 | p1: ^2 ^1 ^8 ^16 | p2: ^32 ^4 ^2 ^1
// ---------------------------------------------------------------------------
__global__ __launch_bounds__(64) void scan_kernel(
    const float* __restrict__ llrnat, float* __restrict__ traj,
    float* __restrict__ state, int ngroups, int first) {
  const int l = threadIdx.x;
  const int b0 = l & 1, b1 = (l >> 1) & 1, b2 = (l >> 2) & 1;
  const int b3 = (l >> 3) & 1, b4 = (l >> 4) & 1, b5 = (l >> 5) & 1;
  // per-phase within-group llr offsets (verified lane-by-lane)
  const int P0O1 =       b3 + 2*b4 + 4*b5 + 8*b2 + 16*b1 + 32*b0;
  const int P0O2 = 64  + 32*b3 + 16*b0 + 8*b1 + 4*b2 + 2*b5 + b4;
  const int P0O3 = 128 + 32*b4 + 16*b3 + 8*b0 + 4*b1 + 2*b2 + b5;
  const int P0O4 = 192 + 32*b5 + 16*b4 + 8*b3 + 4*b0 + 2*b1 + b2;
  const int P1O1 =       b1 + 2*b0 + 4*b3 + 8*b4 + 16*b5 + 32*b2;
  const int P1O2 = 64  + 32*b1 + 16*b2 + 8*b5 + 4*b4 + 2*b3 + b0;
  const int P1O3 = 128 + 32*b0 + 16*b1 + 8*b2 + 4*b5 + 2*b4 + b3;
  const int P1O4 = 192 + 32*b3 + 16*b0 + 8*b1 + 4*b2 + 2*b5 + b4;
  const int P2O1 =       b5 + 2*b2 + 4*b1 + 8*b0 + 16*b3 + 32*b4;
  const int P2O2 = 64  + 32*b5 + 16*b4 + 8*b3 + 4*b0 + 2*b1 + b2;
  const int P2O3 = 128 + 32*b2 + 16*b5 + 8*b4 + 4*b3 + 2*b0 + b1;
  const int P2O4 = 192 + 32*b1 + 16*b2 + 8*b5 + 4*b4 + 2*b3 + b0;

  float prob = first ? 0.0f : state[l];

#define GBODY(r1, r2, r3, r4, S1, L2, L3, L4, gidx)        \
  do {                                                     \
    traj[(size_t)(gidx) * 64 + l] = prob;                  \
    float A_ = prob + (r1); float W_ = S1(A_);             \
    float t0_ = W_ + (r2);  float u1_ = L2(t0_);           \
    float t2_ = u1_ + (r3); float u2_ = L3(t2_);           \
    float t4_ = u2_ + (r4); prob = L4(t4_);                \
  } while (0)

#define LOADBLK(s, blk)                                                         \
  do { const float* gb_ = llrnat + (size_t)(blk) * 768;                         \
    R[s][0] = gb_[P0O1];       R[s][1] = gb_[P0O2];                             \
    R[s][2] = gb_[P0O3];       R[s][3] = gb_[P0O4];                             \
    R[s][4] = gb_[256 + P1O1]; R[s][5] = gb_[256 + P1O2];                       \
    R[s][6] = gb_[256 + P1O3]; R[s][7] = gb_[256 + P1O4];                       \
    R[s][8] = gb_[512 + P2O1]; R[s][9] = gb_[512 + P2O2];                       \
    R[s][10] = gb_[512 + P2O3]; R[s][11] = gb_[512 + P2O4]; } while (0)

  const int nblocks = ngroups / 3;
  const int rem = ngroups - 3 * nblocks;
  const int Bm = (nblocks / PF_B) * PF_B;

  float R[PF_B][12];
#pragma unroll
  for (int s = 0; s < PF_B; ++s) LOADBLK(s, s);

  for (int B = 0; B < Bm; B += PF_B) {
#pragma unroll
    for (int s = 0; s < PF_B; ++s) {
      float r0 = R[s][0], r1 = R[s][1], r2 = R[s][2], r3 = R[s][3];
      float r4 = R[s][4], r5 = R[s][5], r6 = R[s][6], r7 = R[s][7];
      float r8 = R[s][8], r9 = R[s][9], r10 = R[s][10], r11 = R[s][11];
      LOADBLK(s, B + s + PF_B);   // pads allocated past the end
      const int g = 3 * (B + s);
      GBODY(r0, r1, r2, r3,   MINX8,  minx16, minx32, MINX4,  g);
      GBODY(r4, r5, r6, r7,   MINX2,  MINX1,  MINX8,  minx16, g + 1);
      GBODY(r8, r9, r10, r11, minx32, MINX4,  MINX2,  MINX1,  g + 2);
    }
  }
  for (int B = Bm; B < nblocks; ++B) {   // leftover whole blocks (< PF_B)
    const float* gb = llrnat + (size_t)B * 768;
    const int g = 3 * B;
    GBODY(gb[P0O1], gb[P0O2], gb[P0O3], gb[P0O4],             MINX8,  minx16, minx32, MINX4,  g);
    GBODY(gb[256+P1O1], gb[256+P1O2], gb[256+P1O3], gb[256+P1O4], MINX2, MINX1, MINX8, minx16, g + 1);
    GBODY(gb[512+P2O1], gb[512+P2O2], gb[512+P2O3], gb[512+P2O4], minx32, MINX4, MINX2, MINX1, g + 2);
  }
  {  // tail groups (ngroups % 3): phases 0 then 1; only in the final chunk
    const int gd = 3 * nblocks;
    if (rem > 0) {
      const float* gb = llrnat + (size_t)gd * 256;
      GBODY(gb[P0O1], gb[P0O2], gb[P0O3], gb[P0O4], MINX8, minx16, minx32, MINX4, gd);
    }
    if (rem > 1) {
      const float* gb = llrnat + (size_t)(gd + 1) * 256;
      GBODY(gb[P1O1], gb[P1O2], gb[P1O3], gb[P1O4], MINX2, MINX1, MINX8, minx16, gd + 1);
    }
  }
  state[l] = prob;
#undef GBODY
#undef LOADBLK
}

// ---------------------------------------------------------------------------
// Kernel 3: per-t bit.  Un-permute boundary row with sigma_{g%3}^-1, rebuild
// r=t&3 local trellis steps (exact reference op order), strict-< argmin parity.
// ---------------------------------------------------------------------------
__global__ __launch_bounds__(256) void bits_kernel(
    const float* __restrict__ traj, const float* __restrict__ llrnat,
    float* __restrict__ out, int n) {
  int t = blockIdx.x * 256 + threadIdx.x;
  if (t >= n) return;
  int g = t >> 2, r = t & 3, p = g % 3;
  const float* row64 = traj + (size_t)g * 64;
  float cur[32];
  if (p == 0) {
#pragma unroll
    for (int j = 0; j < 32; ++j) {
      int j0 = j & 1, j1 = (j >> 1) & 1, j2 = (j >> 2) & 1, j3 = (j >> 3) & 1, j4 = (j >> 4) & 1;
      cur[j] = row64[8 * j0 + 16 * j1 + 32 * j2 + 4 * j3 + 2 * j4];
    }
  } else if (p == 1) {
#pragma unroll
    for (int j = 0; j < 32; ++j) {
      int j0 = j & 1, j1 = (j >> 1) & 1, j2 = (j >> 2) & 1, j3 = (j >> 3) & 1, j4 = (j >> 4) & 1;
      cur[j] = row64[2 * j0 + j1 + 8 * j2 + 16 * j3 + 32 * j4];
    }
  } else {
#pragma unroll
    for (int j = 0; j < 32; ++j) {
      int j0 = j & 1, j1 = (j >> 1) & 1, j2 = (j >> 2) & 1, j3 = (j >> 3) & 1, j4 = (j >> 4) & 1;
      cur[j] = row64[32 * j0 + 4 * j1 + 2 * j2 + j3 + 8 * j4];
    }
  }
  for (int q = 0; q < r; ++q) {
    const float* L = llrnat + (size_t)(4 * g + q) * 64;
    float nw[32];
#pragma unroll
    for (int j = 0; j < 32; ++j) {
      nw[j] = fminf(cur[(2 * j) & 31] + L[2 * j], cur[(2 * j + 1) & 31] + L[2 * j + 1]);
    }
#pragma unroll
    for (int j = 0; j < 32; ++j) cur[j] = nw[j];
  }
  float best = cur[0]; int bi = 0;
#pragma unroll
  for (int i = 1; i < 32; ++i) {
    if (cur[i] < best) { best = cur[i]; bi = i; }   // first-index tie-break
  }
  out[t] = (float)(bi & 1);
}

// ---------------------------------------------------------------------------
extern "C" void kernel_launch(void* const* d_in, const int* in_sizes, int n_in,
                              void* d_out, int out_size, void* d_ws, size_t ws_size,
                              hipStream_t stream) {
  const float* rx = (const float*)d_in[0];
  const float* W1 = (const float*)d_in[1];
  const float* b1 = (const float*)d_in[2];
  const float* W2 = (const float*)d_in[3];
  const float* b2 = (const float*)d_in[4];
  const float* W3 = (const float*)d_in[5];
  const float* b3 = (const float*)d_in[6];
  float* out = (float*)d_out;

  // Chunk size: full T if it fits, else a multiple of 3072 (keeps every
  // non-final chunk's group count divisible by 3 -> each chunk starts phase 0).
  int CH = -1;
  {
    size_t need = ((size_t)T_TOTAL * 64 + PAD_F) * 4 + ((size_t)T_TOTAL / 4) * 64 * 4 + 1024;
    if (need <= ws_size) CH = T_TOTAL;
  }
  if (CH < 0) {
    for (int m = T_TOTAL / 3072; m >= 1; --m) {
      int c = 3072 * m;
      size_t need = ((size_t)c * 64 + PAD_F) * 4 + ((size_t)c / 4) * 64 * 4 + 1024;
      if (need <= ws_size) { CH = c; break; }
    }
  }
  if (CH < 0) CH = 3072;

  float* llrnat = (float*)d_ws;
  float* traj   = llrnat + ((size_t)CH * 64 + PAD_F);
  float* state  = traj + ((size_t)CH / 4) * 64;

  for (int t0 = 0; t0 < T_TOTAL; t0 += CH) {
    int c = (T_TOTAL - t0 < CH) ? (T_TOTAL - t0) : CH;   // remainder is a mult of 1024
    mlp_kernel <<<c / 256, 256, 0, stream>>>(rx + t0, W1, b1, W2, b2, W3, b3, llrnat, c);
    scan_kernel<<<1, 64, 0, stream>>>(llrnat, traj, state, c / 4, (t0 == 0) ? 1 : 0);
    bits_kernel<<<c / 256, 256, 0, stream>>>(traj, llrnat, out + t0, c);
  }
}

// Round 6
// 3018.906 us; speedup vs baseline: 2.6629x; 1.0611x over previous
//
#include <hip/hip_runtime.h>

#define T_TOTAL 131072
#define NH1 64
#define NH2 32
#define NS 64
#define PF_B 4            // prefetch depth in 3-group (12-step) blocks
#define PADW 3072         // scanllr tail pad (floats) = PF_B blocks

// ---------------------------------------------------------------------------
// Kernel 1: MLP priors.  llr[t][s] = -( relu(relu(x*W1+b1)@W2+b2)@W3+b3 )[s]
// UNCHANGED since round 1 (absmax 0.0) — do not perturb arithmetic.
// ---------------------------------------------------------------------------
__global__ __launch_bounds__(256) void mlp_kernel(
    const float* __restrict__ rx, const float* __restrict__ W1,
    const float* __restrict__ b1, const float* __restrict__ W2,
    const float* __restrict__ b2, const float* __restrict__ W3,
    const float* __restrict__ b3, float* __restrict__ llr, int n) {
#pragma clang fp contract(on)
  __shared__ float sW2[NH1 * NH2], sW3[NH2 * NS];
  __shared__ float sW1[NH1], sb1[NH1], sb2[NH2], sb3[NS];
  int tid = threadIdx.x;
  for (int i = tid; i < NH1 * NH2; i += 256) sW2[i] = W2[i];
  for (int i = tid; i < NH2 * NS; i += 256) sW3[i] = W3[i];
  if (tid < NH1) { sW1[tid] = W1[tid]; sb1[tid] = b1[tid]; }
  if (tid < NH2) sb2[tid] = b2[tid];
  if (tid < NS)  sb3[tid] = b3[tid];
  __syncthreads();

  int t = blockIdx.x * 256 + tid;
  if (t >= n) return;
  float x = rx[t];

  float h1[NH1];
#pragma unroll
  for (int j = 0; j < NH1; ++j) {
    float p = x * sW1[j];
    float s = p + sb1[j];
    h1[j] = fmaxf(s, 0.0f);
  }
  float h2[NH2];
#pragma unroll
  for (int k = 0; k < NH2; ++k) {
    float acc = 0.0f;
#pragma unroll
    for (int j = 0; j < NH1; ++j) acc += h1[j] * sW2[j * NH2 + k];
    float s = acc + sb2[k];
    h2[k] = fmaxf(s, 0.0f);
  }
#pragma unroll
  for (int s_ = 0; s_ < NS; ++s_) {
    float acc = 0.0f;
#pragma unroll
    for (int k = 0; k < NH2; ++k) acc += h2[k] * sW3[k * NS + s_];
    float o = acc + sb3[s_];
    llr[(size_t)t * NS + s_] = -o;
  }
}

// ---------------------------------------------------------------------------
// Kernel 2: pack llr into the scan's lane order: scanllr[t*64+l] =
// llrnat[t*64 + perm_{t%6}(l)].  Only 6 distinct perms (P1O3=P0O1, P1O4=P0O2,
// P2O1=P0O3(form), ... verified); perm id = t%6.  Makes the scan's 12 loads
// per block a single base + imm offsets, perfectly coalesced.
// ---------------------------------------------------------------------------
__global__ __launch_bounds__(256) void pack_kernel(
    const float* __restrict__ llrnat, float* __restrict__ scanllr, int n) {
  int id = blockIdx.x * 256 + threadIdx.x;
  if (id >= n * 64) return;
  int t = id >> 6, l = id & 63;
  // SH[p][j] = target bit position of lane-bit j
  static const int SH[6][6] = {
    {5,4,3,0,1,2},   // P0O1 (= P1O3)
    {4,3,2,5,0,1},   // P0O2 (= P1O4)
    {3,2,1,4,5,0},   // P0O3 (= P2O1 form)
    {2,1,0,3,4,5},   // P0O4 (= P2O2)
    {1,0,5,2,3,4},   // P1O1 (= P2O3)
    {0,5,4,1,2,3},   // P1O2 (= P2O4)
  };
  const int* s = SH[t % 6];
  int idx = ((l & 1) << s[0]) | (((l >> 1) & 1) << s[1]) | (((l >> 2) & 1) << s[2])
          | (((l >> 3) & 1) << s[3]) | (((l >> 4) & 1) << s[4]) | (((l >> 5) & 1) << s[5]);
  scanllr[(size_t)t * 64 + l] = llrnat[(size_t)t * 64 + idx];
}

// ---------------------------------------------------------------------------
// Cross-lane pair-min helpers.  All SYMMETRIC (convention-independent).
// ---------------------------------------------------------------------------
#define DPPF(x, c) __builtin_amdgcn_mov_dpp((x), (c), 0xF, 0xF, true)
__device__ __forceinline__ float xf1(float v) { return __int_as_float(DPPF(__float_as_int(v), 0xB1)); }              // ^1
__device__ __forceinline__ float xf2(float v) { return __int_as_float(DPPF(__float_as_int(v), 0x4E)); }              // ^2
__device__ __forceinline__ float xf4(float v) { return __int_as_float(DPPF(DPPF(__float_as_int(v), 0x141), 0x1B)); } // ^7,^3 = ^4
__device__ __forceinline__ float xf8(float v) { return __int_as_float(DPPF(__float_as_int(v), 0x128)); }             // row_ror:8 = ^8
#define MINX1(v) fminf((v), xf1(v))
#define MINX2(v) fminf((v), xf2(v))
#define MINX4(v) fminf((v), xf4(v))
#define MINX8(v) fminf((v), xf8(v))

typedef unsigned int uint2v __attribute__((ext_vector_type(2)));
#if __has_builtin(__builtin_amdgcn_permlane16_swap) && __has_builtin(__builtin_amdgcn_permlane32_swap)
__device__ __forceinline__ float minx16(float v) {
  uint2v pr = __builtin_amdgcn_permlane16_swap(__float_as_uint(v), __float_as_uint(v), false, false);
  return fminf(__uint_as_float(pr[0]), __uint_as_float(pr[1]));  // = min(x[l], x[l^16])
}
__device__ __forceinline__ float minx32(float v) {
  uint2v pr = __builtin_amdgcn_permlane32_swap(__float_as_uint(v), __float_as_uint(v), false, false);
  return fminf(__uint_as_float(pr[0]), __uint_as_float(pr[1]));  // = min(x[l], x[l^32])
}
#else
__device__ __forceinline__ float minx16(float v) {
  int a = (((int)threadIdx.x ^ 16) & 63) << 2;
  return fminf(v, __int_as_float(__builtin_amdgcn_ds_bpermute(a, __float_as_int(v))));
}
__device__ __forceinline__ float minx32(float v) {
  int a = (((int)threadIdx.x ^ 32) & 63) << 2;
  return fminf(v, __int_as_float(__builtin_amdgcn_ds_bpermute(a, __float_as_int(v))));
}
#endif

// ---------------------------------------------------------------------------
// Kernel 3: sequential Viterbi recurrence, 4 steps/group, zero distribute,
// rotating lane layout (3-phase cycle) — arithmetic IDENTICAL to round 5
// (absmax 0.0); only operand addressing and traj store layout changed.
// Boundary rows batched 4 groups per float4 into transposed trajT[l][g].
// ---------------------------------------------------------------------------
__global__ __launch_bounds__(64) void scan_kernel(
    const float* __restrict__ scanllr, float* __restrict__ trajT,
    float* __restrict__ state, int ngroups, int gstride, int first) {
  const int l = threadIdx.x;
  float prob = first ? 0.0f : state[l];
  const float* sp = scanllr + l;
  float* tr = trajT + (size_t)l * gstride;
  float tb0 = 0.0f, tb1 = 0.0f, tb2 = 0.0f;

#define GBODY(r1, r2, r3, r4, S1, L2, L3, L4, SLOT, GV)        \
  do {                                                         \
    if ((SLOT) == 0) tb0 = prob;                               \
    else if ((SLOT) == 1) tb1 = prob;                          \
    else if ((SLOT) == 2) tb2 = prob;                          \
    else { float4 pv_ = make_float4(tb0, tb1, tb2, prob);      \
           *(float4*)(tr + ((GV) - 3)) = pv_; }                \
    float A_ = prob + (r1); float W_ = S1(A_);                 \
    float t0_ = W_ + (r2);  float u1_ = L2(t0_);               \
    float t2_ = u1_ + (r3); float u2_ = L3(t2_);               \
    float t4_ = u2_ + (r4); prob = L4(t4_);                    \
  } while (0)

#define GBODYS(r1, r2, r3, r4, S1, L2, L3, L4, GV)             \
  do {                                                         \
    tr[(GV)] = prob;                                           \
    float A_ = prob + (r1); float W_ = S1(A_);                 \
    float t0_ = W_ + (r2);  float u1_ = L2(t0_);               \
    float t2_ = u1_ + (r3); float u2_ = L3(t2_);               \
    float t4_ = u2_ + (r4); prob = L4(t4_);                    \
  } while (0)

// one 3-group block: consume R[s], refill slot s from block B+s+PF_B
#define BLK3(s, SL0, SL1, SL2, GBASE)                                     \
  { float r0 = R[s][0], r1 = R[s][1], r2 = R[s][2], r3 = R[s][3],         \
          r4 = R[s][4], r5 = R[s][5], r6 = R[s][6], r7 = R[s][7],         \
          r8 = R[s][8], r9 = R[s][9], r10 = R[s][10], r11 = R[s][11];     \
    const float* nb_ = sp + (size_t)(B + (s) + PF_B) * 768;               \
    _Pragma("unroll") for (int w = 0; w < 12; ++w) R[s][w] = nb_[w * 64]; \
    GBODY(r0, r1, r2, r3,   MINX8,  minx16, minx32, MINX4,  SL0, (GBASE));     \
    GBODY(r4, r5, r6, r7,   MINX2,  MINX1,  MINX8,  minx16, SL1, (GBASE) + 1); \
    GBODY(r8, r9, r10, r11, minx32, MINX4,  MINX2,  MINX1,  SL2, (GBASE) + 2); \
  }

  const int nblocks = ngroups / 3;
  const int rem = ngroups - 3 * nblocks;
  const int Bm = (nblocks / PF_B) * PF_B;

  float R[PF_B][12];
#pragma unroll
  for (int s = 0; s < PF_B; ++s) {
    const float* b = sp + (size_t)s * 768;
#pragma unroll
    for (int w = 0; w < 12; ++w) R[s][w] = b[w * 64];
  }

  for (int B = 0; B < Bm; B += PF_B) {     // 12 groups per iter; g%4 pattern static
    BLK3(0, 0, 1, 2, 3 * B);
    BLK3(1, 3, 0, 1, 3 * B + 3);
    BLK3(2, 2, 3, 0, 3 * B + 6);
    BLK3(3, 1, 2, 3, 3 * B + 9);
  }
  for (int B2 = Bm; B2 < nblocks; ++B2) {  // leftover whole blocks (scalar stores)
    const float* gb = sp + (size_t)B2 * 768;
    const int g = 3 * B2;
    GBODYS(gb[0], gb[64], gb[128], gb[192],        MINX8,  minx16, minx32, MINX4,  g);
    GBODYS(gb[256], gb[320], gb[384], gb[448],     MINX2,  MINX1,  MINX8,  minx16, g + 1);
    GBODYS(gb[512], gb[576], gb[640], gb[704],     minx32, MINX4,  MINX2,  MINX1,  g + 2);
  }
  {  // tail groups (ngroups % 3): phases 0 then 1; only in the final chunk
    const float* gb = sp + (size_t)nblocks * 768;
    const int gd = 3 * nblocks;
    if (rem > 0)
      GBODYS(gb[0], gb[64], gb[128], gb[192],      MINX8,  minx16, minx32, MINX4,  gd);
    if (rem > 1)
      GBODYS(gb[256], gb[320], gb[384], gb[448],   MINX2,  MINX1,  MINX8,  minx16, gd + 1);
  }
  state[l] = prob;
#undef GBODY
#undef GBODYS
#undef BLK3
}

// ---------------------------------------------------------------------------
// Kernel 4: per-t bit.  Un-permute boundary row with sigma_{g%3}^-1 (now from
// transposed trajT[l][g]), rebuild r=t&3 local trellis steps (exact reference
// op order), strict-< argmin parity.
// ---------------------------------------------------------------------------
__global__ __launch_bounds__(256) void bits_kernel(
    const float* __restrict__ trajT, const float* __restrict__ llrnat,
    float* __restrict__ out, int n, int gstride) {
  int t = blockIdx.x * 256 + threadIdx.x;
  if (t >= n) return;
  int g = t >> 2, r = t & 3, p = g % 3;
  float cur[32];
  if (p == 0) {
#pragma unroll
    for (int j = 0; j < 32; ++j) {
      int j0 = j & 1, j1 = (j >> 1) & 1, j2 = (j >> 2) & 1, j3 = (j >> 3) & 1, j4 = (j >> 4) & 1;
      int lm = 8 * j0 + 16 * j1 + 32 * j2 + 4 * j3 + 2 * j4;
      cur[j] = trajT[(size_t)lm * gstride + g];
    }
  } else if (p == 1) {
#pragma unroll
    for (int j = 0; j < 32; ++j) {
      int j0 = j & 1, j1 = (j >> 1) & 1, j2 = (j >> 2) & 1, j3 = (j >> 3) & 1, j4 = (j >> 4) & 1;
      int lm = 2 * j0 + j1 + 8 * j2 + 16 * j3 + 32 * j4;
      cur[j] = trajT[(size_t)lm * gstride + g];
    }
  } else {
#pragma unroll
    for (int j = 0; j < 32; ++j) {
      int j0 = j & 1, j1 = (j >> 1) & 1, j2 = (j >> 2) & 1, j3 = (j >> 3) & 1, j4 = (j >> 4) & 1;
      int lm = 32 * j0 + 4 * j1 + 2 * j2 + j3 + 8 * j4;
      cur[j] = trajT[(size_t)lm * gstride + g];
    }
  }
  for (int q = 0; q < r; ++q) {
    const float* L = llrnat + (size_t)(4 * g + q) * 64;
    float nw[32];
#pragma unroll
    for (int j = 0; j < 32; ++j) {
      nw[j] = fminf(cur[(2 * j) & 31] + L[2 * j], cur[(2 * j + 1) & 31] + L[2 * j + 1]);
    }
#pragma unroll
    for (int j = 0; j < 32; ++j) cur[j] = nw[j];
  }
  float best = cur[0]; int bi = 0;
#pragma unroll
  for (int i = 1; i < 32; ++i) {
    if (cur[i] < best) { best = cur[i]; bi = i; }   // first-index tie-break
  }
  out[t] = (float)(bi & 1);
}

// ---------------------------------------------------------------------------
extern "C" void kernel_launch(void* const* d_in, const int* in_sizes, int n_in,
                              void* d_out, int out_size, void* d_ws, size_t ws_size,
                              hipStream_t stream) {
  const float* rx = (const float*)d_in[0];
  const float* W1 = (const float*)d_in[1];
  const float* b1 = (const float*)d_in[2];
  const float* W2 = (const float*)d_in[3];
  const float* b2 = (const float*)d_in[4];
  const float* W3 = (const float*)d_in[5];
  const float* b3 = (const float*)d_in[6];
  float* out = (float*)d_out;

  // ws: llrnat(CH*64) + scanllr(CH*64 + PADW) + trajT(64 * CH/4) + state
  int CH = -1;
  {
    size_t nd = (size_t)T_TOTAL * 64 * 4 + ((size_t)T_TOTAL * 64 + PADW) * 4
              + (size_t)64 * (T_TOTAL / 4) * 4 + 1024;
    if (nd <= ws_size) CH = T_TOTAL;
  }
  if (CH < 0) {
    for (int m = T_TOTAL / 3072; m >= 1; --m) {
      int c = 3072 * m;
      size_t nd = (size_t)c * 64 * 4 + ((size_t)c * 64 + PADW) * 4
                + (size_t)64 * (c / 4) * 4 + 1024;
      if (nd <= ws_size) { CH = c; break; }
    }
  }
  if (CH < 0) CH = 3072;
  const int GS = CH / 4;

  float* llrnat  = (float*)d_ws;
  float* scanllr = llrnat + (size_t)CH * 64;
  float* trajT   = scanllr + (size_t)CH * 64 + PADW;
  float* state   = trajT + (size_t)64 * GS;

  for (int t0 = 0; t0 < T_TOTAL; t0 += CH) {
    int c = (T_TOTAL - t0 < CH) ? (T_TOTAL - t0) : CH;  // mult of 1024; groups mult of 4
    mlp_kernel <<<c / 256, 256, 0, stream>>>(rx + t0, W1, b1, W2, b2, W3, b3, llrnat, c);
    pack_kernel<<<c / 4, 256, 0, stream>>>(llrnat, scanllr, c);
    scan_kernel<<<1, 64, 0, stream>>>(scanllr, trajT, state, c / 4, GS, (t0 == 0) ? 1 : 0);
    bits_kernel<<<c / 256, 256, 0, stream>>>(trajT, llrnat, out + t0, c, GS);
  }
}

// Round 7
// 2583.357 us; speedup vs baseline: 3.1118x; 1.1686x over previous
//
#include <hip/hip_runtime.h>

#define T_TOTAL 131072
#define NH1 64
#define NH2 32
#define NS 64
#define PF_B 4            // scan prefetch depth, in 12-step blocks

// ---------------------------------------------------------------------------
// Kernel 1: MLP priors.  llr[t][s] = -( relu(relu(x*W1+b1)@W2+b2)@W3+b3 )[s]
// UNCHANGED since round 1 (absmax 0.0) — do not perturb arithmetic.
// ---------------------------------------------------------------------------
__global__ __launch_bounds__(256) void mlp_kernel(
    const float* __restrict__ rx, const float* __restrict__ W1,
    const float* __restrict__ b1, const float* __restrict__ W2,
    const float* __restrict__ b2, const float* __restrict__ W3,
    const float* __restrict__ b3, float* __restrict__ llr, int n) {
#pragma clang fp contract(on)
  __shared__ float sW2[NH1 * NH2], sW3[NH2 * NS];
  __shared__ float sW1[NH1], sb1[NH1], sb2[NH2], sb3[NS];
  int tid = threadIdx.x;
  for (int i = tid; i < NH1 * NH2; i += 256) sW2[i] = W2[i];
  for (int i = tid; i < NH2 * NS; i += 256) sW3[i] = W3[i];
  if (tid < NH1) { sW1[tid] = W1[tid]; sb1[tid] = b1[tid]; }
  if (tid < NH2) sb2[tid] = b2[tid];
  if (tid < NS)  sb3[tid] = b3[tid];
  __syncthreads();

  int t = blockIdx.x * 256 + tid;
  if (t >= n) return;
  float x = rx[t];

  float h1[NH1];
#pragma unroll
  for (int j = 0; j < NH1; ++j) {
    float p = x * sW1[j];
    float s = p + sb1[j];
    h1[j] = fmaxf(s, 0.0f);
  }
  float h2[NH2];
#pragma unroll
  for (int k = 0; k < NH2; ++k) {
    float acc = 0.0f;
#pragma unroll
    for (int j = 0; j < NH1; ++j) acc += h1[j] * sW2[j * NH2 + k];
    float s = acc + sb2[k];
    h2[k] = fmaxf(s, 0.0f);
  }
#pragma unroll
  for (int s_ = 0; s_ < NS; ++s_) {
    float acc = 0.0f;
#pragma unroll
    for (int k = 0; k < NH2; ++k) acc += h2[k] * sW3[k * NS + s_];
    float o = acc + sb3[s_];
    llr[(size_t)t * NS + s_] = -o;
  }
}

// ---------------------------------------------------------------------------
// Kernel 2: pack llr into per-lane float4 blocks for the scan:
//   sllr2[b*768 + q*256 + l*4 + j] = llrnat[(12b+4q+j)*64 + perm_{(4q+j)%6}(l)]
// Same SH perm table as round 6 (verified absmax 0.0 there).
// ---------------------------------------------------------------------------
__global__ __launch_bounds__(256) void pack_kernel(
    const float* __restrict__ llrnat, float4* __restrict__ sllr2,
    int nsteps, int npblocks) {
  int id = blockIdx.x * 256 + threadIdx.x;
  if (id >= npblocks * 192) return;
  int b = id / 192, rq = id % 192, q = rq >> 6, l = rq & 63;
  static const int SH[6][6] = {
    {5,4,3,0,1,2}, {4,3,2,5,0,1}, {3,2,1,4,5,0},
    {2,1,0,3,4,5}, {1,0,5,2,3,4}, {0,5,4,1,2,3},
  };
  float v[4];
#pragma unroll
  for (int j = 0; j < 4; ++j) {
    int step = 12 * b + 4 * q + j;
    if (step >= nsteps) step = nsteps - 1;   // clamped pad (values unused)
    const int* s = SH[(4 * q + j) % 6];
    int idx = ((l & 1) << s[0]) | (((l >> 1) & 1) << s[1]) | (((l >> 2) & 1) << s[2])
            | (((l >> 3) & 1) << s[3]) | (((l >> 4) & 1) << s[4]) | (((l >> 5) & 1) << s[5]);
    v[j] = llrnat[(size_t)step * 64 + idx];
  }
  sllr2[(size_t)b * 192 + q * 64 + l] = make_float4(v[0], v[1], v[2], v[3]);
}

// ---------------------------------------------------------------------------
// Fused route+min helpers.  asm v_min_f32_dpp = single chain op; s_nop 1
// supplies the required 2 wait states for the VALU->DPP read hazard (the
// compiler cannot see inside inline asm).  All ops are symmetric pair-mins.
// ---------------------------------------------------------------------------
#define DPPF(x, c) __builtin_amdgcn_mov_dpp((x), (c), 0xF, 0xF, true)
__device__ __forceinline__ float amin1(float t) {
  float o; asm("s_nop 1\n\tv_min_f32_dpp %0, %1, %1 quad_perm:[1,0,3,2] row_mask:0xf bank_mask:0xf"
               : "=v"(o) : "v"(t)); return o;
}
__device__ __forceinline__ float amin2(float t) {
  float o; asm("s_nop 1\n\tv_min_f32_dpp %0, %1, %1 quad_perm:[2,3,0,1] row_mask:0xf bank_mask:0xf"
               : "=v"(o) : "v"(t)); return o;
}
__device__ __forceinline__ float amin8(float t) {
  float o; asm("s_nop 1\n\tv_min_f32_dpp %0, %1, %1 row_ror:8 row_mask:0xf bank_mask:0xf"
               : "=v"(o) : "v"(t)); return o;
}
__device__ __forceinline__ float amin4(float t) {
  float u = __int_as_float(DPPF(__float_as_int(t), 0x141));   // t[l^7]
  float o; asm("s_nop 1\n\tv_min_f32_dpp %0, %1, %2 quad_perm:[3,2,1,0] row_mask:0xf bank_mask:0xf"
               : "=v"(o) : "v"(u), "v"(t)); return o;          // min(t[l^4], t)
}

typedef unsigned int uint2v __attribute__((ext_vector_type(2)));
#if __has_builtin(__builtin_amdgcn_permlane16_swap) && __has_builtin(__builtin_amdgcn_permlane32_swap)
__device__ __forceinline__ float minx16(float v) {
  uint2v pr = __builtin_amdgcn_permlane16_swap(__float_as_uint(v), __float_as_uint(v), false, false);
  return fminf(__uint_as_float(pr[0]), __uint_as_float(pr[1]));
}
__device__ __forceinline__ float minx32(float v) {
  uint2v pr = __builtin_amdgcn_permlane32_swap(__float_as_uint(v), __float_as_uint(v), false, false);
  return fminf(__uint_as_float(pr[0]), __uint_as_float(pr[1]));
}
#else
__device__ __forceinline__ float minx16(float v) {
  int a = (((int)threadIdx.x ^ 16) & 63) << 2;
  return fminf(v, __int_as_float(__builtin_amdgcn_ds_bpermute(a, __float_as_int(v))));
}
__device__ __forceinline__ float minx32(float v) {
  int a = (((int)threadIdx.x ^ 32) & 63) << 2;
  return fminf(v, __int_as_float(__builtin_amdgcn_ds_bpermute(a, __float_as_int(v))));
}
#endif

// ---------------------------------------------------------------------------
// Kernel 3: sequential Viterbi recurrence.  Arithmetic (operands + op order)
// IDENTICAL to round 6 (absmax 0.0): per step { t = prob + r ; prob =
// pair-min over mask m }.  Mask schedule per 12-step block:
//   group0: 8,16,32,4 | group1: 2,1,8,16 | group2: 32,4,2,1
// Boundary row stored once per block (pre-update, phase-0 layout).
// ---------------------------------------------------------------------------
__global__ __launch_bounds__(64) void scan_kernel(
    const float4* __restrict__ sllr2, float* __restrict__ trajB,
    float* __restrict__ state, int nblocks, int rem, int first) {
  const int l = threadIdx.x;
  float prob = first ? 0.0f : state[l];
  const float4* sp = sllr2 + l;        // lane-stride 16B; block stride 192 f4
  float* tb = trajB + l;

#define GROUP(qv, M1, M2, M3, M4)                   \
  do { float t_;                                    \
    t_ = prob + (qv).x; prob = M1(t_);              \
    t_ = prob + (qv).y; prob = M2(t_);              \
    t_ = prob + (qv).z; prob = M3(t_);              \
    t_ = prob + (qv).w; prob = M4(t_);              \
  } while (0)

#define BLKBODY(q0, q1, q2, BIDX)                   \
  do { tb[(size_t)(BIDX) * 64] = prob;              \
    GROUP(q0, amin8,  minx16, minx32, amin4);       \
    GROUP(q1, amin2,  amin1,  amin8,  minx16);      \
    GROUP(q2, minx32, amin4,  amin2,  amin1);       \
  } while (0)

  const int Bm = (nblocks / PF_B) * PF_B;
  float4 Q[PF_B][3];
#pragma unroll
  for (int s = 0; s < PF_B; ++s) {
#pragma unroll
    for (int q = 0; q < 3; ++q) Q[s][q] = sp[(size_t)s * 192 + q * 64];
  }

  for (int B = 0; B < Bm; B += PF_B) {
#pragma unroll
    for (int s = 0; s < PF_B; ++s) {
      float4 q0 = Q[s][0], q1 = Q[s][1], q2 = Q[s][2];
      {  // refill slot s with block B+s+PF_B (pads allocated past the end)
        const float4* nb = sp + (size_t)(B + s + PF_B) * 192;
        Q[s][0] = nb[0]; Q[s][1] = nb[64]; Q[s][2] = nb[128];
      }
      BLKBODY(q0, q1, q2, B + s);
    }
  }
  for (int B2 = Bm; B2 < nblocks; ++B2) {   // leftover blocks, direct loads
    const float4* nb = sp + (size_t)B2 * 192;
    float4 q0 = nb[0], q1 = nb[64], q2 = nb[128];
    BLKBODY(q0, q1, q2, B2);
  }
  if (rem > 0) {  // tail groups (<3): store boundary, run phase0 (+phase1)
    const float4* nb = sp + (size_t)nblocks * 192;
    tb[(size_t)nblocks * 64] = prob;
    float4 q0 = nb[0];
    GROUP(q0, amin8, minx16, minx32, amin4);
    if (rem > 1) {
      float4 q1 = nb[64];
      GROUP(q1, amin2, amin1, amin8, minx16);
    }
  }
  state[l] = prob;
#undef GROUP
#undef BLKBODY
}

// ---------------------------------------------------------------------------
// Kernel 4: per-t bit.  Un-permute block-boundary row with sigma0^-1 (r5/r6
// verified formula), rebuild r = t%12 local trellis steps (exact reference op
// order), strict-< argmin parity (first-index tie-break).
// ---------------------------------------------------------------------------
__global__ __launch_bounds__(256) void bits_kernel(
    const float* __restrict__ trajB, const float* __restrict__ llrnat,
    float* __restrict__ out, int n) {
  int t = blockIdx.x * 256 + threadIdx.x;
  if (t >= n) return;
  int bk = t / 12, r = t % 12;
  const float* row64 = trajB + (size_t)bk * 64;
  float cur[32];
#pragma unroll
  for (int j = 0; j < 32; ++j) {
    int j0 = j & 1, j1 = (j >> 1) & 1, j2 = (j >> 2) & 1, j3 = (j >> 3) & 1, j4 = (j >> 4) & 1;
    cur[j] = row64[8 * j0 + 16 * j1 + 32 * j2 + 4 * j3 + 2 * j4];
  }
  for (int q = 0; q < r; ++q) {
    const float* L = llrnat + (size_t)(12 * bk + q) * 64;
    float nw[32];
#pragma unroll
    for (int j = 0; j < 32; ++j) {
      nw[j] = fminf(cur[(2 * j) & 31] + L[2 * j], cur[(2 * j + 1) & 31] + L[2 * j + 1]);
    }
#pragma unroll
    for (int j = 0; j < 32; ++j) cur[j] = nw[j];
  }
  float best = cur[0]; int bi = 0;
#pragma unroll
  for (int i = 1; i < 32; ++i) {
    if (cur[i] < best) { best = cur[i]; bi = i; }
  }
  out[t] = (float)(bi & 1);
}

// ---------------------------------------------------------------------------
extern "C" void kernel_launch(void* const* d_in, const int* in_sizes, int n_in,
                              void* d_out, int out_size, void* d_ws, size_t ws_size,
                              hipStream_t stream) {
  const float* rx = (const float*)d_in[0];
  const float* W1 = (const float*)d_in[1];
  const float* b1 = (const float*)d_in[2];
  const float* W2 = (const float*)d_in[3];
  const float* b2 = (const float*)d_in[4];
  const float* W3 = (const float*)d_in[5];
  const float* b3 = (const float*)d_in[6];
  float* out = (float*)d_out;

  // ws: llrnat(CH*64) + sllr2((ceil(CH/12)+PF_B+1)*768) + trajB((CH/12+2)*64) + state
#define NEED(c) ((size_t)(c) * 64 * 4 \
               + ((size_t)(((c) + 11) / 12) + PF_B + 1) * 768 * 4 \
               + ((size_t)(c) / 12 + 2) * 64 * 4 + 1024)
  int CH = -1;
  if (NEED(T_TOTAL) <= ws_size) CH = T_TOTAL;
  if (CH < 0) {
    for (int m = T_TOTAL / 3072; m >= 1; --m) {
      int c = 3072 * m;
      if (NEED(c) <= ws_size) { CH = c; break; }
    }
  }
  if (CH < 0) CH = 3072;
#undef NEED

  float*  llrnat = (float*)d_ws;
  float4* sllr2  = (float4*)(llrnat + (size_t)CH * 64);
  float*  trajB  = (float*)(sllr2 + ((size_t)((CH + 11) / 12) + PF_B + 1) * 192);
  float*  state  = trajB + ((size_t)CH / 12 + 2) * 64;

  for (int t0 = 0; t0 < T_TOTAL; t0 += CH) {
    int c = (T_TOTAL - t0 < CH) ? (T_TOTAL - t0) : CH;  // multiple of 1024
    int npb = (c + 11) / 12;
    int nblocks = c / 4 / 3;            // whole 12-step blocks
    int rem = c / 4 - 3 * nblocks;      // leftover 4-step groups (0..2)
    mlp_kernel <<<c / 256, 256, 0, stream>>>(rx + t0, W1, b1, W2, b2, W3, b3, llrnat, c);
    pack_kernel<<<(npb * 192 + 255) / 256, 256, 0, stream>>>(llrnat, sllr2, c, npb);
    scan_kernel<<<1, 64, 0, stream>>>(sllr2, trajB, state, nblocks, rem, (t0 == 0) ? 1 : 0);
    bits_kernel<<<c / 256, 256, 0, stream>>>(trajB, llrnat, out + t0, c);
  }
}